// Round 2
// baseline (80.974 us; speedup 1.0000x reference)
//
#include <hip/hip_runtime.h>
#include <hip/hip_bf16.h>

// OscillatorBank: DDSP-style additive synth.
//   f0        [8,500,1]  f32
//   loudness  [8,500,1]  f32
//   harm_amps [8,500,60] f32
// out: signal [8,128000] f32
//
// Math: upsample-by-256 (linear, align_corners=True) of per-frame angular
// increments, cumsum -> phases, sum_h loud*amp*sin(phase).
// Key identity: increment(n,h) = k_h*(2pi/SR)*lerp(f0)(n), so
//   phase(n,h) = k_h*(2pi/SR) * V(n),  V(n) = cumsum of lerp(f0).
// V(n) = H[b][t] + cnt*f0[t] + (f0[t+1]-f0[t])*FracSum  (closed form per frame),
// with H = exclusive prefix over frame totals (only 8 x 499 scan, kernel 1).
// Index math pos = n*499/127999 is done in exact integer arithmetic.
// Inner loop works in REVOLUTIONS (v_sin_f32 native units): rev_k = frac(k*phf),
// phf = frac(V/16000) computed once in f64 per thread.

#define NHARM 60
#define TFRAMES 500
#define TM1 499          // T-1 (number of interp frames 0..498)
#define LOUT 128000      // 500*256
#define LM1U 127999u

__global__ __launch_bounds__(512) void osc_prefix_kernel(const float* __restrict__ f0,
                                                         double* __restrict__ H) {
    int b = blockIdx.x;          // 8 blocks
    int tid = threadIdx.x;       // 512 threads, t = tid
    double g = 0.0;
    if (tid < TM1) {
        unsigned t = (unsigned)tid;
        unsigned a   = (t * LM1U + 498u) / 499u;                   // first sample of frame t
        unsigned end = (t < TM1 - 1u) ? ((t + 1u) * LM1U + 498u) / 499u - 1u
                                      : LM1U;                      // last frame holds clamped tail
        unsigned cnt   = end - a + 1u;
        unsigned rem_a = a * 499u - t * LM1U;                      // 499*a - t*127999, in [0,498]
        // sum of frac over frame = (cnt*rem_a + 499*cnt*(cnt-1)/2)/127999  (exact < 2^25)
        unsigned num = cnt * rem_a + 499u * (cnt * (cnt - 1u) / 2u);
        double F = (double)num / 127999.0;
        double fa = (double)f0[b * TFRAMES + tid];
        double fb = (double)f0[b * TFRAMES + tid + 1];
        g = (double)cnt * fa + (fb - fa) * F;                      // frame total (f0 units)
    }
    __shared__ double sd[512];
    sd[tid] = g;
    __syncthreads();
    // Hillis-Steele inclusive scan over 512 (only first 499 meaningful)
    for (int off = 1; off < 512; off <<= 1) {
        double v = sd[tid];
        double o = (tid >= off) ? sd[tid - off] : 0.0;
        __syncthreads();
        sd[tid] = v + o;
        __syncthreads();
    }
    if (tid < TM1) H[b * TM1 + tid] = sd[tid] - g;                 // exclusive prefix
}

__global__ __launch_bounds__(256) void osc_main_kernel(const float* __restrict__ f0,
                                                       const float* __restrict__ loud,
                                                       const float* __restrict__ amps,
                                                       const double* __restrict__ H,
                                                       float* __restrict__ out) {
    const int b = blockIdx.y;
    const int n = blockIdx.x * 256 + threadIdx.x;   // 500 blocks * 256 = 128000

    // exact index math: pos = n*499/127999
    unsigned p = (unsigned)n * 499u;                // <= 63,871,501
    unsigned q = p / LM1U;                          // magic-mul div
    unsigned t = q > 498u ? 498u : q;               // clamp (only n=LM1 hits)
    unsigned rem = p - t * LM1U;                    // frac = rem/127999 (1.0 at tail)
    unsigned a = (t * LM1U + 498u) / 499u;          // first sample of frame t
    unsigned rem_a = a * 499u - t * LM1U;
    unsigned cnt = (unsigned)n - a + 1u;            // samples a..n within frame
    unsigned num = cnt * rem_a + 499u * (cnt * (cnt - 1u) / 2u);
    double F = (double)num / 127999.0;              // sum of frac over a..n (exact num)

    const float f0a = f0[b * TFRAMES + t];
    const float f0b = f0[b * TFRAMES + t + 1];
    double U = (double)cnt * (double)f0a + ((double)f0b - (double)f0a) * F;
    double V = H[b * TM1 + t] + U;                  // cumsum of lerp(f0) through sample n

    const float fracf = (float)rem * (1.0f / 127999.0f);
    const float la = loud[b * TFRAMES + t];
    const float lb = loud[b * TFRAMES + t + 1];
    const float ln = la + fracf * (lb - la);

    // phase(k) = 2*pi * k * V/16000  ->  revolutions(k) = k * (V/16000)
    const double rev1 = V * (1.0 / 16000.0);
    const float  phf  = (float)(rev1 - floor(rev1));   // frac revolutions for k=1

    const float* __restrict__ ampA = amps + ((size_t)b * TFRAMES + t) * NHARM;
    const float* __restrict__ ampB = ampA + NHARM;

    // Nyquist cutoff: k > 8000/f0 masked on both frame nodes -> contribution 0.
    // +1 guard keeps any borderline-k inside the loop; per-k mask below is exact.
    const float fmin = fminf(f0a, f0b);
    const int hmax = min(NHARM, (int)(8000.0f / fmin) + 1);

    float accA = 0.f, accB = 0.f;
#pragma unroll 4
    for (int h = 0; h < hmax; ++h) {
        const float kf = (float)(h + 1);
        float rv = phf * kf;
        rv -= floorf(rv);                              // v_fract
        const float sv = __builtin_amdgcn_sinf(rv);    // v_sin_f32: sin(2*pi*rv)
        const float aa = (f0a * kf > 8000.f) ? 0.f : ampA[h];  // exact ref mask semantics
        const float ab = (f0b * kf > 8000.f) ? 0.f : ampB[h];
        accA += aa * sv;
        accB += ab * sv;
    }
    const float acc = accA + fracf * (accB - accA);    // lerp commutes with the h-sum
    out[(size_t)b * LOUT + n] = acc * ln;              // loudness factors out of the h-sum
}

extern "C" void kernel_launch(void* const* d_in, const int* in_sizes, int n_in,
                              void* d_out, int out_size, void* d_ws, size_t ws_size,
                              hipStream_t stream) {
    const float* f0   = (const float*)d_in[0];
    const float* loud = (const float*)d_in[1];
    const float* amps = (const float*)d_in[2];
    double* H  = (double*)d_ws;                     // 8*499*8 = 31,936 B
    float* out = (float*)d_out;

    osc_prefix_kernel<<<dim3(8), dim3(512), 0, stream>>>(f0, H);
    osc_main_kernel<<<dim3(500, 8), dim3(256), 0, stream>>>(f0, loud, amps, H, out);
}

// Round 3
// 75.785 us; speedup vs baseline: 1.0685x; 1.0685x over previous
//
#include <hip/hip_runtime.h>
#include <hip/hip_bf16.h>

// OscillatorBank: DDSP-style additive synth.
//   f0 [8,500,1] f32, loudness [8,500,1] f32, harm_amps [8,500,60] f32
// out: signal [8,128000] f32
//
// phase(n,h) = k_h*(2pi/SR) * V(n), V(n) = cumsum of lerp(f0)  (closed form per
// frame + 8x499 exclusive prefix H from kernel 1). Index math n*499/127999 is
// exact integer arithmetic. Inner loop in REVOLUTIONS (v_sin_f32 native):
// rev_k = frac(k*phf), phf = frac(V/16000) in f64 once per thread.
// Amp rows are staged in LDS pre-masked (Nyquist f0*k>8000, exact ref f32
// semantics) -> inner loop has zero global loads and zero compares.

#define NHARM 60
#define TFRAMES 500
#define TM1 499          // T-1 (number of interp frames 0..498)
#define LOUT 128000      // 500*256
#define LM1U 127999u

__global__ __launch_bounds__(512) void osc_prefix_kernel(const float* __restrict__ f0,
                                                         double* __restrict__ H) {
    int b = blockIdx.x;          // 8 blocks
    int tid = threadIdx.x;       // 512 threads, t = tid
    double g = 0.0;
    if (tid < TM1) {
        unsigned t = (unsigned)tid;
        unsigned a   = (t * LM1U + 498u) / 499u;                   // first sample of frame t
        unsigned end = (t < TM1 - 1u) ? ((t + 1u) * LM1U + 498u) / 499u - 1u
                                      : LM1U;                      // last frame holds clamped tail
        unsigned cnt   = end - a + 1u;
        unsigned rem_a = a * 499u - t * LM1U;                      // in [0,498]
        // sum of frac over frame = (cnt*rem_a + 499*cnt*(cnt-1)/2)/127999 (exact < 2^25)
        unsigned num = cnt * rem_a + 499u * (cnt * (cnt - 1u) / 2u);
        double F = (double)num / 127999.0;
        double fa = (double)f0[b * TFRAMES + tid];
        double fb = (double)f0[b * TFRAMES + tid + 1];
        g = (double)cnt * fa + (fb - fa) * F;                      // frame total (f0 units)
    }
    __shared__ double sd[512];
    sd[tid] = g;
    __syncthreads();
    for (int off = 1; off < 512; off <<= 1) {                     // Hillis-Steele
        double v = sd[tid];
        double o = (tid >= off) ? sd[tid - off] : 0.0;
        __syncthreads();
        sd[tid] = v + o;
        __syncthreads();
    }
    if (tid < TM1) H[b * TM1 + tid] = sd[tid] - g;                 // exclusive prefix
}

__global__ __launch_bounds__(256) void osc_main_kernel(const float* __restrict__ f0,
                                                       const float* __restrict__ loud,
                                                       const float* __restrict__ amps,
                                                       const double* __restrict__ H,
                                                       float* __restrict__ out) {
    const int b   = blockIdx.y;
    const int tid = threadIdx.x;
    const int base = blockIdx.x * 256;
    const int n   = base + tid;                      // 500 blocks * 256 = 128000

    // ---- stage pre-masked amp rows t0..t0+2 into LDS (block spans <=2 frames) ----
    unsigned t0 = (unsigned)base * 499u / LM1U;      // frame of first sample
    if (t0 > 498u) t0 = 498u;
    __shared__ float sAmp[3][64];                    // 60 used, 64 stride
    if (tid < 192) {
        const int r = tid >> 6, c = tid & 63;
        if (c < NHARM) {
            const unsigned row = min(t0 + (unsigned)r, 499u);
            const float fr = f0[b * TFRAMES + row];
            const float av = amps[((size_t)b * TFRAMES + row) * NHARM + c];
            const float kf = (float)(c + 1);
            sAmp[r][c] = (fr * kf > 8000.f) ? 0.f : av;   // exact ref mask semantics
        }
    }
    __syncthreads();

    // ---- exact index math: pos = n*499/127999 ----
    unsigned p = (unsigned)n * 499u;
    unsigned q = p / LM1U;
    unsigned t = q > 498u ? 498u : q;                // clamp (only n=127999 hits)
    unsigned rem = p - t * LM1U;                     // frac = rem/127999
    unsigned a = (t * LM1U + 498u) / 499u;           // first sample of frame t
    unsigned rem_a = a * 499u - t * LM1U;
    unsigned cnt = (unsigned)n - a + 1u;             // samples a..n within frame
    unsigned num = cnt * rem_a + 499u * (cnt * (cnt - 1u) / 2u);
    double F = (double)num / 127999.0;               // sum of frac over a..n (exact num)

    const float f0a = f0[b * TFRAMES + t];
    const float f0b = f0[b * TFRAMES + t + 1];
    double U = (double)cnt * (double)f0a + ((double)f0b - (double)f0a) * F;
    double V = H[b * TM1 + t] + U;                   // cumsum of lerp(f0) through n

    const float fracf = (float)rem * (1.0f / 127999.0f);
    const float la = loud[b * TFRAMES + t];
    const float lb = loud[b * TFRAMES + t + 1];
    const float ln = la + fracf * (lb - la);

    // phase(k) = 2*pi*k*V/16000  ->  revolutions(k) = k * frac(V/16000)
    const double rev1 = V * (1.0 / 16000.0);
    const float  phf  = (float)(rev1 - floor(rev1));

    // Nyquist early-exit (masked entries are 0, so this is purely perf;
    // formula proven to cover every kept harmonic)
    const float fmin = fminf(f0a, f0b);
    const int hmax = min(NHARM, (int)(8000.0f / fmin) + 1);

    const float* __restrict__ lsA = &sAmp[t - t0][0];     // broadcast reads
    const float* __restrict__ lsB = &sAmp[t - t0 + 1][0];

    float accA = 0.f, accB = 0.f;
#pragma unroll 4
    for (int h = 0; h < hmax; ++h) {
        const float kf = (float)(h + 1);
        float rv = phf * kf;
        rv -= floorf(rv);                             // v_fract
        const float sv = __builtin_amdgcn_sinf(rv);   // sin(2*pi*rv)
        accA += lsA[h] * sv;
        accB += lsB[h] * sv;
    }
    const float acc = accA + fracf * (accB - accA);   // lerp commutes with h-sum
    out[(size_t)b * LOUT + n] = acc * ln;             // loudness factors out
}

extern "C" void kernel_launch(void* const* d_in, const int* in_sizes, int n_in,
                              void* d_out, int out_size, void* d_ws, size_t ws_size,
                              hipStream_t stream) {
    const float* f0   = (const float*)d_in[0];
    const float* loud = (const float*)d_in[1];
    const float* amps = (const float*)d_in[2];
    double* H  = (double*)d_ws;                     // 8*499*8 = 31,936 B
    float* out = (float*)d_out;

    osc_prefix_kernel<<<dim3(8), dim3(512), 0, stream>>>(f0, H);
    osc_main_kernel<<<dim3(500, 8), dim3(256), 0, stream>>>(f0, loud, amps, H, out);
}

// Round 4
// 75.022 us; speedup vs baseline: 1.0793x; 1.0102x over previous
//
#include <hip/hip_runtime.h>
#include <hip/hip_bf16.h>

// OscillatorBank: DDSP-style additive synth.
//   f0 [8,500,1] f32, loudness [8,500,1] f32, harm_amps [8,500,60] f32
// out: signal [8,128000] f32
//
// phase(n,h) = k_h*(2pi/SR) * V(n), V(n) = cumsum of lerp(f0)  (closed form per
// frame + 8x499 exclusive prefix H from kernel 1). Index math n*499/127999 is
// exact integer arithmetic. Inner loop in REVOLUTIONS (v_sin_f32 native):
// rev_k = frac(k*phf), phf = frac(V/16000) in f64 once per sample.
// Each thread produces TWO adjacent samples (halves wave count, amortizes the
// f64 prologue, float2-coalesced store). Amp rows staged in LDS pre-masked
// (Nyquist f0*k>8000, exact ref f32 semantics) as interleaved {A,B} float2
// pairs -> one ds_read_b64 per (sample,harmonic) pair slot, zero compares.

#define NHARM 60
#define TFRAMES 500
#define TM1 499          // T-1 (number of interp frames 0..498)
#define LOUT 128000      // 500*256
#define LM1U 127999u

__global__ __launch_bounds__(512) void osc_prefix_kernel(const float* __restrict__ f0,
                                                         double* __restrict__ H) {
    int b = blockIdx.x;          // 8 blocks
    int tid = threadIdx.x;       // 512 threads, t = tid
    double g = 0.0;
    if (tid < TM1) {
        unsigned t = (unsigned)tid;
        unsigned a   = (t * LM1U + 498u) / 499u;                   // first sample of frame t
        unsigned end = (t < TM1 - 1u) ? ((t + 1u) * LM1U + 498u) / 499u - 1u
                                      : LM1U;                      // last frame holds clamped tail
        unsigned cnt   = end - a + 1u;
        unsigned rem_a = a * 499u - t * LM1U;                      // in [0,498]
        // sum of frac over frame = (cnt*rem_a + 499*cnt*(cnt-1)/2)/127999 (exact < 2^25)
        unsigned num = cnt * rem_a + 499u * (cnt * (cnt - 1u) / 2u);
        double F = (double)num / 127999.0;
        double fa = (double)f0[b * TFRAMES + tid];
        double fb = (double)f0[b * TFRAMES + tid + 1];
        g = (double)cnt * fa + (fb - fa) * F;                      // frame total (f0 units)
    }
    __shared__ double sd[512];
    sd[tid] = g;
    __syncthreads();
    for (int off = 1; off < 512; off <<= 1) {                     // Hillis-Steele
        double v = sd[tid];
        double o = (tid >= off) ? sd[tid - off] : 0.0;
        __syncthreads();
        sd[tid] = v + o;
        __syncthreads();
    }
    if (tid < TM1) H[b * TM1 + tid] = sd[tid] - g;                 // exclusive prefix
}

__global__ __launch_bounds__(256) void osc_main_kernel(const float* __restrict__ f0,
                                                       const float* __restrict__ loud,
                                                       const float* __restrict__ amps,
                                                       const double* __restrict__ H,
                                                       float* __restrict__ out) {
    const int b    = blockIdx.y;
    const int tid  = threadIdx.x;
    const int base = blockIdx.x * 512;               // 250 blocks * 512 samples
    const int n0   = base + 2 * tid;                 // this thread: samples n0, n0+1

    // ---- stage pre-masked amp {A,B} pairs for frames t0..t0+2 into LDS ----
    // block spans 512 samples ~ 2.0 frames -> t in {t0, t0+1, t0+2}
    unsigned t0 = (unsigned)base * 499u / LM1U;
    if (t0 > 498u) t0 = 498u;
    __shared__ float2 sPair[3][64];                  // [t-t0][h] = {amp[t][h], amp[t+1][h]} masked
    if (tid < 192) {
        const int r = tid >> 6, c = tid & 63;
        if (c < NHARM) {
            const unsigned ra = min(t0 + (unsigned)r, 499u);
            const unsigned rb = min(ra + 1u, 499u);
            const float fa = f0[b * TFRAMES + ra];
            const float fb = f0[b * TFRAMES + rb];
            const float va = amps[((size_t)b * TFRAMES + ra) * NHARM + c];
            const float vb = amps[((size_t)b * TFRAMES + rb) * NHARM + c];
            const float kf = (float)(c + 1);
            sPair[r][c] = make_float2((fa * kf > 8000.f) ? 0.f : va,   // exact ref mask
                                      (fb * kf > 8000.f) ? 0.f : vb);
        }
    }
    __syncthreads();

    // ---- per-sample closed-form phase/lerp state (exact integer index math) ----
    float phf[2], frw[2], lnv[2], fmn[2];
    const float2* pbase[2];
#pragma unroll
    for (int s = 0; s < 2; ++s) {
        const int n = n0 + s;
        unsigned p = (unsigned)n * 499u;             // pos numerator
        unsigned t = p / LM1U;                       // magic-mul div
        if (t > 498u) t = 498u;                      // clamp (only n=127999)
        unsigned rem = p - t * LM1U;                 // frac = rem/127999
        unsigned a = (t * LM1U + 498u) / 499u;       // first sample of frame t
        unsigned rem_a = a * 499u - t * LM1U;
        unsigned cnt = (unsigned)n - a + 1u;         // samples a..n within frame
        unsigned num = cnt * rem_a + 499u * (cnt * (cnt - 1u) / 2u);
        double F = (double)num / 127999.0;           // sum of frac over a..n (exact num)

        const float f0a = f0[b * TFRAMES + t];
        const float f0b = f0[b * TFRAMES + t + 1];
        double U = (double)cnt * (double)f0a + ((double)f0b - (double)f0a) * F;
        double V = H[b * TM1 + t] + U;               // cumsum of lerp(f0) through n

        const float fracf = (float)rem * (1.0f / 127999.0f);
        const float la = loud[b * TFRAMES + t];
        const float lb = loud[b * TFRAMES + t + 1];

        // phase(k) = 2*pi*k*V/16000 -> revolutions(k) = k * frac(V/16000)
        const double rev1 = V * (1.0 / 16000.0);
        phf[s] = (float)(rev1 - floor(rev1));
        frw[s] = fracf;
        lnv[s] = la + fracf * (lb - la);
        fmn[s] = fminf(f0a, f0b);
        pbase[s] = &sPair[t - t0][0];
    }

    // Nyquist early-exit (masked entries are 0, purely perf; +1 guard)
    const int hm = min(NHARM, (int)(8000.0f / fminf(fmn[0], fmn[1])) + 1);

    const float2* __restrict__ p0 = pbase[0];
    const float2* __restrict__ p1 = pbase[1];
    float a0A = 0.f, a0B = 0.f, a1A = 0.f, a1B = 0.f;
#pragma unroll 4
    for (int h = 0; h < hm; ++h) {
        const float kf = (float)(h + 1);
        float r0 = phf[0] * kf; r0 -= floorf(r0);    // v_fract
        float r1 = phf[1] * kf; r1 -= floorf(r1);
        const float s0 = __builtin_amdgcn_sinf(r0);  // sin(2*pi*rv)
        const float s1 = __builtin_amdgcn_sinf(r1);
        const float2 ab0 = p0[h];                    // ds_read_b64, broadcast
        const float2 ab1 = p1[h];
        a0A += ab0.x * s0; a0B += ab0.y * s0;
        a1A += ab1.x * s1; a1B += ab1.y * s1;
    }
    const float acc0 = a0A + frw[0] * (a0B - a0A);   // lerp commutes with h-sum
    const float acc1 = a1A + frw[1] * (a1B - a1A);
    float2 o = make_float2(acc0 * lnv[0], acc1 * lnv[1]);
    *reinterpret_cast<float2*>(&out[(size_t)b * LOUT + n0]) = o;   // 8B coalesced
}

extern "C" void kernel_launch(void* const* d_in, const int* in_sizes, int n_in,
                              void* d_out, int out_size, void* d_ws, size_t ws_size,
                              hipStream_t stream) {
    const float* f0   = (const float*)d_in[0];
    const float* loud = (const float*)d_in[1];
    const float* amps = (const float*)d_in[2];
    double* H  = (double*)d_ws;                     // 8*499*8 = 31,936 B
    float* out = (float*)d_out;

    osc_prefix_kernel<<<dim3(8), dim3(512), 0, stream>>>(f0, H);
    osc_main_kernel<<<dim3(250, 8), dim3(256), 0, stream>>>(f0, loud, amps, H, out);
}

// Round 5
// 74.581 us; speedup vs baseline: 1.0857x; 1.0059x over previous
//
#include <hip/hip_runtime.h>
#include <hip/hip_bf16.h>

// OscillatorBank, single fused kernel.
//   f0 [8,500,1] f32, loudness [8,500,1] f32, harm_amps [8,500,60] f32
// out: signal [8,128000] f32
//
// phase(n,h) = k_h*(2pi/SR)*V(n), V(n) = cumsum of lerp(f0). Closed form per
// frame; each block needs only H[t0..t0+2] (exclusive prefix of frame totals),
// which wave 0 computes by REDUCTION over <=500 frame totals (8/lane, f64,
// shfl-reduce) while threads 64..255 stage Nyquist-masked amp {A,B} float2
// pairs into LDS. One __syncthreads, then 2 samples/thread in revolutions
// (v_sin_f32 native units). Index math n*499/127999 is exact integer
// arithmetic; f64 divides replaced by reciprocal-mul (rel err ~2e-16).

#define NHARM 60
#define TFRAMES 500
#define LOUT 128000      // 500*256
#define LM1U 127999u
#define INV_LM1 (1.0 / 127999.0)

// frame total g[t] = sum over samples in frame t of lerp(f0): cnt*fa + (fb-fa)*F
__device__ __forceinline__ double frame_total(const float* __restrict__ f0,
                                              int b, unsigned t) {
    unsigned a   = (t * LM1U + 498u) / 499u;                   // first sample of frame t
    unsigned end = (t < 498u) ? ((t + 1u) * LM1U + 498u) / 499u - 1u
                              : LM1U;                          // last frame holds clamped tail
    unsigned cnt   = end - a + 1u;
    unsigned rem_a = a * 499u - t * LM1U;                      // in [0,498]
    unsigned num = cnt * rem_a + 499u * (cnt * (cnt - 1u) / 2u);  // exact < 2^25
    double F = (double)num * INV_LM1;
    double fa = (double)f0[b * TFRAMES + (int)t];
    double fb = (double)f0[b * TFRAMES + (int)t + 1];
    return (double)cnt * fa + (fb - fa) * F;
}

__global__ __launch_bounds__(256) void osc_fused_kernel(const float* __restrict__ f0,
                                                        const float* __restrict__ loud,
                                                        const float* __restrict__ amps,
                                                        float* __restrict__ out) {
    const int b    = blockIdx.y;
    const int tid  = threadIdx.x;
    const int base = blockIdx.x * 512;               // 250 blocks * 512 samples
    const int n0   = base + 2 * tid;                 // this thread: samples n0, n0+1

    unsigned t0 = (unsigned)base * 499u / LM1U;      // frame of first sample (<=497)
    if (t0 > 498u) t0 = 498u;

    __shared__ float2 sPair[3][64];                  // [r][h] = masked {amp[t0+r][h], amp[t0+r+1][h]}
    __shared__ double gsh[2];                        // g[t0], g[t0+1]
    __shared__ double Ssh;                           // sum_{t'<t0} g[t']

    if (tid < 64) {
        // ---- wave 0: H reduction (frame totals t' < t0+2) ----
        const unsigned tlim = min(t0 + 2u, 499u);
        double psum = 0.0;
        for (unsigned tp = (unsigned)tid; tp < tlim; tp += 64u) {
            const double g = frame_total(f0, b, tp);
            if (tp < t0) psum += g;
            else         gsh[tp - t0] = g;           // tp == t0 or t0+1
        }
#pragma unroll
        for (int off = 32; off > 0; off >>= 1)       // wave64 shfl reduce (f64)
            psum += __shfl_down(psum, off, 64);
        if (tid == 0) Ssh = psum;
    } else if (tid < 256) {
        // ---- threads 64..255: stage Nyquist-masked amp pairs ----
        const int r = (tid - 64) >> 6, c = (tid - 64) & 63;
        if (c < NHARM) {
            const unsigned ra = min(t0 + (unsigned)r, 499u);
            const unsigned rb = min(ra + 1u, 499u);
            const float fa = f0[b * TFRAMES + ra];
            const float fb = f0[b * TFRAMES + rb];
            const float va = amps[((size_t)b * TFRAMES + ra) * NHARM + c];
            const float vb = amps[((size_t)b * TFRAMES + rb) * NHARM + c];
            const float kf = (float)(c + 1);
            sPair[r][c] = make_float2((fa * kf > 8000.f) ? 0.f : va,   // exact ref mask
                                      (fb * kf > 8000.f) ? 0.f : vb);
        }
    }
    __syncthreads();

    const double S  = Ssh;
    const double g0 = gsh[0];
    const double g1 = gsh[1];

    // ---- per-sample closed-form phase/lerp state (exact integer index math) ----
    float phf[2], frw[2], lnv[2], fmn[2];
    const float2* pbase[2];
#pragma unroll
    for (int s = 0; s < 2; ++s) {
        const int n = n0 + s;
        unsigned p = (unsigned)n * 499u;             // pos numerator
        unsigned t = p / LM1U;                       // magic-mul div
        if (t > 498u) t = 498u;                      // clamp (only n=127999)
        unsigned rem = p - t * LM1U;                 // frac = rem/127999
        unsigned a = (t * LM1U + 498u) / 499u;       // first sample of frame t
        unsigned rem_a = a * 499u - t * LM1U;
        unsigned cnt = (unsigned)n - a + 1u;         // samples a..n within frame
        unsigned num = cnt * rem_a + 499u * (cnt * (cnt - 1u) / 2u);
        double F = (double)num * INV_LM1;            // sum of frac over a..n

        const float f0a = f0[b * TFRAMES + t];
        const float f0b = f0[b * TFRAMES + t + 1];
        double U = (double)cnt * (double)f0a + ((double)f0b - (double)f0a) * F;
        const unsigned r = t - t0;                   // 0..2
        double Hv = S;
        if (r > 0u) Hv += g0;
        if (r > 1u) Hv += g1;
        double V = Hv + U;                           // cumsum of lerp(f0) through n

        const float fracf = (float)rem * (1.0f / 127999.0f);
        const float la = loud[b * TFRAMES + t];
        const float lb = loud[b * TFRAMES + t + 1];

        // phase(k) = 2*pi*k*V/16000 -> revolutions(k) = k * frac(V/16000)
        const double rev1 = V * (1.0 / 16000.0);
        phf[s] = (float)(rev1 - floor(rev1));
        frw[s] = fracf;
        lnv[s] = la + fracf * (lb - la);
        fmn[s] = fminf(f0a, f0b);
        pbase[s] = &sPair[r][0];
    }

    // Nyquist early-exit (masked entries are 0, purely perf; +1 guard)
    const int hm = min(NHARM, (int)(8000.0f / fminf(fmn[0], fmn[1])) + 1);

    const float2* __restrict__ p0 = pbase[0];
    const float2* __restrict__ p1 = pbase[1];
    float a0A = 0.f, a0B = 0.f, a1A = 0.f, a1B = 0.f;
#pragma unroll 4
    for (int h = 0; h < hm; ++h) {
        const float kf = (float)(h + 1);
        float r0 = phf[0] * kf; r0 -= floorf(r0);    // v_fract
        float r1 = phf[1] * kf; r1 -= floorf(r1);
        const float s0 = __builtin_amdgcn_sinf(r0);  // sin(2*pi*rv)
        const float s1 = __builtin_amdgcn_sinf(r1);
        const float2 ab0 = p0[h];                    // ds_read_b64, broadcast
        const float2 ab1 = p1[h];
        a0A += ab0.x * s0; a0B += ab0.y * s0;
        a1A += ab1.x * s1; a1B += ab1.y * s1;
    }
    const float acc0 = a0A + frw[0] * (a0B - a0A);   // lerp commutes with h-sum
    const float acc1 = a1A + frw[1] * (a1B - a1A);
    float2 o = make_float2(acc0 * lnv[0], acc1 * lnv[1]);
    *reinterpret_cast<float2*>(&out[(size_t)b * LOUT + n0]) = o;   // 8B coalesced
}

extern "C" void kernel_launch(void* const* d_in, const int* in_sizes, int n_in,
                              void* d_out, int out_size, void* d_ws, size_t ws_size,
                              hipStream_t stream) {
    const float* f0   = (const float*)d_in[0];
    const float* loud = (const float*)d_in[1];
    const float* amps = (const float*)d_in[2];
    float* out = (float*)d_out;

    osc_fused_kernel<<<dim3(250, 8), dim3(256), 0, stream>>>(f0, loud, amps, out);
}